// Round 13
// baseline (162.503 us; speedup 1.0000x reference)
//
#include <hip/hip_runtime.h>

// 3-layer GCN on MI355X.
// Structure: per-node normalization factored (aggregate pre-scaled values),
// adjacency = fixed-capacity buckets, no count/scan:
//   memset(cursor) -> k_fill (cursor ends = in-degree)
//   -> k_gemm12 (agg1 + L1 + L2 linear -> t2s) -> k_agg2 -> k_agg3.
// R13: gemm12 phase B = MB=16 (1250 blocks, no grid tail) x wave-partitioned
// W2 (4 waves x disjoint 32-col slices, W2 read once/block from L2, register
// double-buffer, ZERO k-loop barriers) with only h1 on the LDS pipe
// (2 b128/k4 vs R8's 6 — the measured LDS-issue bottleneck).
// Lessons: R3 atomic scatter=186us; R4 grid.sync~100us; R7 register W2 with
// 8x intra-block redundancy = L2-BW-bound; R9/R11 MB=32 = grid tail; R10
// wave-count bug (4 waves per 256t block!); macro params must not be 'w'.

constexpr int NN  = 20000;  // nodes
constexpr int NE  = 320000; // edges
constexpr int F0  = 10;     // input feats
constexpr int F1  = 256;    // layer1 out
constexpr int F2  = 128;    // layer2 out
constexpr int MB  = 16;     // nodes per gemm12 tile
constexpr int CAP = 64;     // bucket capacity (max in-deg ~36, P(>=64)~2e-18)

// ---------- adjacency fill ----------

__global__ void k_fill(const int* __restrict__ src, const int* __restrict__ dst,
                       int* cursor, int* __restrict__ col) {
  int e = blockIdx.x * 256 + threadIdx.x;
  if (e >= NE) return;
  const int d = dst[e], s = src[e];
  const int pos = atomicAdd(&cursor[d], 1) & (CAP - 1);
  col[d * CAP + pos] = s;
}

// ---------- fused: a1 (LDS) -> h1 = relu(a1 W1 + b1) (LDS) -> t2s = dinv*(h1 W2)

__global__ __launch_bounds__(256) void k_gemm12(
    const float* __restrict__ x, const int* __restrict__ cursor,
    const int* __restrict__ col, const float* __restrict__ W1,
    const float* __restrict__ b1, const float* __restrict__ W2,
    float* __restrict__ t2s) {
  __shared__ float alds[MB * F0];   // 640 B
  __shared__ float h1[MB][F1 + 4];  // 16.6 KB; stride 260 -> 8 g-groups hit
                                    // disjoint 4-bank spans: conflict-free
  const int tid = threadIdx.x;
  const int n0 = blockIdx.x * MB;
  // stage 0: layer-1 aggregation into LDS; dinv on the fly from cursor
  {
    const int m = tid >> 4;
    const int f = tid & 15;
    if (f < F0) {
      const int n = n0 + m;
      const int deg = cursor[n];
      const int base = n * CAP;
      const float di = rsqrtf((float)(deg + 1));
      float acc = x[n * F0 + f] * di;  // self-loop
      int k = 0;
      for (; k + 3 < deg; k += 4) {
        const int s0 = col[base + k],     s1 = col[base + k + 1];
        const int s2 = col[base + k + 2], s3 = col[base + k + 3];
        const float d0 = rsqrtf((float)(cursor[s0] + 1));
        const float d1 = rsqrtf((float)(cursor[s1] + 1));
        const float d2 = rsqrtf((float)(cursor[s2] + 1));
        const float d3 = rsqrtf((float)(cursor[s3] + 1));
        acc += x[s0 * F0 + f] * d0 + x[s1 * F0 + f] * d1 +
               x[s2 * F0 + f] * d2 + x[s3 * F0 + f] * d3;
      }
      for (; k < deg; ++k) {
        const int s = col[base + k];
        acc += x[s * F0 + f] * rsqrtf((float)(cursor[s] + 1));
      }
      alds[m * F0 + f] = di * acc;
    }
  }
  __syncthreads();
  {  // phase A: thread = layer-1 channel c; h1[m][c] stride-1 in c
    const int c = tid;
    float w1r[F0];
#pragma unroll
    for (int k = 0; k < F0; ++k) w1r[k] = W1[k * F1 + c];
    const float bb = b1[c];
#pragma unroll
    for (int m = 0; m < MB; ++m) {
      float acc = bb;
#pragma unroll
      for (int k = 0; k < F0; ++k) acc += alds[m * F0 + k] * w1r[k];
      h1[m][c] = fmaxf(acc, 0.f);
    }
  }
  __syncthreads();  // LAST barrier — phase B streams with no syncs
  // phase B: wave wv (of 4) owns cols [32*wv, 32*wv+32): W2 read ONCE per
  // block from L2 (no w2lds, no k-loop barriers, only h1 on the LDS pipe).
  // Lane: nodes {g, g+8} x 4 cols; per k4: 2 ds_read_b128 + 4 global float4
  // (8-lane broadcast) + 32 FMA. W2 regs double-buffered (R7 pattern).
  const int wv = tid >> 6;   // 4 waves
  const int l  = tid & 63;
  const int q  = l & 7;      // 8 col-quads -> 32 cols per wave
  const int g  = l >> 3;     // node-pair base: nodes g, g+8
  const int c0 = wv * 32 + q * 4;
  float aA[4] = {0.f, 0.f, 0.f, 0.f};
  float aB[4] = {0.f, 0.f, 0.f, 0.f};
  const float* w2p = W2 + c0;
  float4 wa0 = *(const float4*)(w2p + 0 * F2);
  float4 wa1 = *(const float4*)(w2p + 1 * F2);
  float4 wa2 = *(const float4*)(w2p + 2 * F2);
  float4 wa3 = *(const float4*)(w2p + 3 * F2);
#define FMA4A(hv, vw4)                                              \
  aA[0] += (hv) * (vw4).x; aA[1] += (hv) * (vw4).y;                 \
  aA[2] += (hv) * (vw4).z; aA[3] += (hv) * (vw4).w;
#define FMA4B(hv, vw4)                                              \
  aB[0] += (hv) * (vw4).x; aB[1] += (hv) * (vw4).y;                 \
  aB[2] += (hv) * (vw4).z; aB[3] += (hv) * (vw4).w;
  for (int k4 = 0; k4 < F1; k4 += 8) {
    // prefetch rows k4+4..k4+7 while computing k4..k4+3
    const float4 wb0 = *(const float4*)(w2p + (size_t)(k4 + 4) * F2);
    const float4 wb1 = *(const float4*)(w2p + (size_t)(k4 + 5) * F2);
    const float4 wb2 = *(const float4*)(w2p + (size_t)(k4 + 6) * F2);
    const float4 wb3 = *(const float4*)(w2p + (size_t)(k4 + 7) * F2);
    {
      const float4 hA = *(const float4*)&h1[g][k4];
      const float4 hB = *(const float4*)&h1[g + 8][k4];
      FMA4A(hA.x, wa0); FMA4A(hA.y, wa1); FMA4A(hA.z, wa2); FMA4A(hA.w, wa3);
      FMA4B(hB.x, wa0); FMA4B(hB.y, wa1); FMA4B(hB.z, wa2); FMA4B(hB.w, wa3);
    }
    if (k4 + 8 < F1) {  // prefetch k4+8..k4+11 while computing k4+4..k4+7
      wa0 = *(const float4*)(w2p + (size_t)(k4 + 8) * F2);
      wa1 = *(const float4*)(w2p + (size_t)(k4 + 9) * F2);
      wa2 = *(const float4*)(w2p + (size_t)(k4 + 10) * F2);
      wa3 = *(const float4*)(w2p + (size_t)(k4 + 11) * F2);
    }
    {
      const float4 hA = *(const float4*)&h1[g][k4 + 4];
      const float4 hB = *(const float4*)&h1[g + 8][k4 + 4];
      FMA4A(hA.x, wb0); FMA4A(hA.y, wb1); FMA4A(hA.z, wb2); FMA4A(hA.w, wb3);
      FMA4B(hB.x, wb0); FMA4B(hB.y, wb1); FMA4B(hB.z, wb2); FMA4B(hB.w, wb3);
    }
  }
#undef FMA4A
#undef FMA4B
  const float dA = rsqrtf((float)(cursor[n0 + g] + 1));
  const float dB = rsqrtf((float)(cursor[n0 + g + 8] + 1));
  *(float4*)&t2s[(size_t)(n0 + g) * F2 + c0] =
      make_float4(aA[0] * dA, aA[1] * dA, aA[2] * dA, aA[3] * dA);
  *(float4*)&t2s[(size_t)(n0 + g + 8) * F2 + c0] =
      make_float4(aB[0] * dB, aB[1] * dB, aB[2] * dB, aB[3] * dB);
}

// ---------- layer-2 aggregation + layer-3 transform ----------
// 2 nodes per wave: half-wave (32 lanes) per node, float4 per lane (512B/row).

__global__ __launch_bounds__(256) void k_agg2(
    const float* __restrict__ t2s, const int* __restrict__ cursor,
    const int* __restrict__ col, const float* __restrict__ b2,
    const float* __restrict__ W3, float* __restrict__ t3s) {
  const int wave = (blockIdx.x * 256 + threadIdx.x) >> 6;
  const int lane = threadIdx.x & 63;
  const int half = lane >> 5;        // 0 or 1
  const int li   = lane & 31;
  const int n    = wave * 2 + half;  // 2500 blocks cover 20000 exactly
  if (n >= NN) return;
  const int deg = cursor[n];
  const int base = n * CAP;
  const int fx = li * 4;
  const float4 vs = *(const float4*)&t2s[(size_t)n * F2 + fx];
  float a0 = vs.x, a1 = vs.y, a2 = vs.z, a3 = vs.w;
  int k = 0;
  for (; k + 3 < deg; k += 4) {  // 4 coalesced 512B gathers in flight
    const int s0 = col[base + k],     s1 = col[base + k + 1];
    const int s2 = col[base + k + 2], s3 = col[base + k + 3];
    const float4 v0 = *(const float4*)&t2s[(size_t)s0 * F2 + fx];
    const float4 v1 = *(const float4*)&t2s[(size_t)s1 * F2 + fx];
    const float4 v2 = *(const float4*)&t2s[(size_t)s2 * F2 + fx];
    const float4 v3 = *(const float4*)&t2s[(size_t)s3 * F2 + fx];
    a0 += (v0.x + v1.x) + (v2.x + v3.x);
    a1 += (v0.y + v1.y) + (v2.y + v3.y);
    a2 += (v0.z + v1.z) + (v2.z + v3.z);
    a3 += (v0.w + v1.w) + (v2.w + v3.w);
  }
  for (; k < deg; ++k) {
    const float4 v = *(const float4*)&t2s[(size_t)col[base + k] * F2 + fx];
    a0 += v.x; a1 += v.y; a2 += v.z; a3 += v.w;
  }
  const float di = rsqrtf((float)(deg + 1));
  const float4 bb = *(const float4*)&b2[fx];
  const float4 w3 = *(const float4*)&W3[fx];
  const float h0 = fmaxf(di * a0 + bb.x, 0.f);
  const float h1 = fmaxf(di * a1 + bb.y, 0.f);
  const float h2 = fmaxf(di * a2 + bb.z, 0.f);
  const float h3 = fmaxf(di * a3 + bb.w, 0.f);
  float p = (h0 * w3.x + h1 * w3.y) + (h2 * w3.z + h3 * w3.w);
#pragma unroll
  for (int off = 16; off > 0; off >>= 1) p += __shfl_down(p, off);  // within half
  if (li == 0) t3s[n] = di * p;
}

// ---------- layer-3 aggregation ----------

__global__ void k_agg3(const float* __restrict__ t3s, const int* __restrict__ cursor,
                       const int* __restrict__ col, const float* __restrict__ b3,
                       float* __restrict__ out) {
  int n = blockIdx.x * 256 + threadIdx.x;
  if (n >= NN) return;
  const int deg = cursor[n];
  const int base = n * CAP;
  float acc = t3s[n];
  int k = 0;
  for (; k + 7 < deg; k += 8)
    acc += ((t3s[col[base + k]] + t3s[col[base + k + 1]]) +
            (t3s[col[base + k + 2]] + t3s[col[base + k + 3]])) +
           ((t3s[col[base + k + 4]] + t3s[col[base + k + 5]]) +
            (t3s[col[base + k + 6]] + t3s[col[base + k + 7]]));
  for (; k < deg; ++k) acc += t3s[col[base + k]];
  out[n] = rsqrtf((float)(deg + 1)) * acc + b3[0];
}

extern "C" void kernel_launch(void* const* d_in, const int* in_sizes, int n_in,
                              void* d_out, int out_size, void* d_ws, size_t ws_size,
                              hipStream_t stream) {
  const float* x = (const float*)d_in[0];
  const int* ei = (const int*)d_in[1];
  const int* srcv = ei;       // edge_index[0]
  const int* dstv = ei + NE;  // edge_index[1]
  const float* W1 = (const float*)d_in[2];
  const float* b1 = (const float*)d_in[3];
  const float* W2 = (const float*)d_in[4];
  const float* b2 = (const float*)d_in[5];
  const float* W3 = (const float*)d_in[6];
  const float* b3 = (const float*)d_in[7];
  float* out = (float*)d_out;

  char* w = (char*)d_ws;
  auto alloc = [&](size_t bytes) -> void* {
    void* p = (void*)w;
    w += (bytes + 255) & ~(size_t)255;
    return p;
  };
  int*   cursor = (int*)  alloc(NN * 4);
  int*   col    = (int*)  alloc((size_t)NN * CAP * 4);
  float* t2s    = (float*)alloc((size_t)NN * F2 * 4);
  float* t3s    = (float*)alloc(NN * 4);

  (void)hipMemsetAsync(cursor, 0, NN * 4, stream);
  k_fill<<<(NE + 255) / 256, 256, 0, stream>>>(srcv, dstv, cursor, col);
  k_gemm12<<<NN / MB, 256, 0, stream>>>(x, cursor, col, W1, b1, W2, t2s);
  k_agg2<<<NN / 8, 256, 0, stream>>>(t2s, cursor, col, b2, W3, t3s);
  k_agg3<<<(NN + 255) / 256, 256, 0, stream>>>(t3s, cursor, col, b3, out);
}